// Round 3
// baseline (229.677 us; speedup 1.0000x reference)
//
#include <hip/hip_runtime.h>
#include <hip/hip_bf16.h>

#define N_NODES 100000
#define E_EDGES 800000
#define LN_EPS 1e-5f

#define P_BLOCKS 256       // partition blocks
#define EPB 3125           // edges per partition block (800000/256, exact)
#define SLICE 64           // nodes per bucket (power of 2: bk = dst>>6)
#define NBK 1563           // ceil(100000/64); number of buckets
#define NBK_PAD 1792       // 7*256 (scan convenience)
#define OFFS_STRIDE 1564   // per-block stored starts incl sentinel
#define QCAP 768           // bucket edge capacity (mean 512, sd 23 -> 11 sigma)
#define CONV_PER_BLOCK 12500   // 3.2M float4 groups of x / 256 convert blocks
#define TILE_BLKS 782      // fused kernel: 782 blocks x 128 nodes (2 buckets each)
#define NBPAD 136          // nbT row stride in shorts: 272B, 16B-aligned, 2-way banks

typedef __attribute__((ext_vector_type(4))) float f32x4;
typedef __attribute__((ext_vector_type(8))) short short8;

__device__ __forceinline__ unsigned short f2bf(float f) {
    __hip_bfloat16 h = __float2bfloat16(f);
    return *reinterpret_cast<unsigned short*>(&h);
}
__device__ __forceinline__ float bflo(unsigned int u) { return __uint_as_float(u << 16); }
__device__ __forceinline__ float bfhi(unsigned int u) { return __uint_as_float(u & 0xffff0000u); }

// ---- pass 1: LDS counting-sort of edges by bucket, coalesced writeback ------
// Blocks [0,256): sort 3125 edges each, write block-major sorted records +
// per-bucket start offsets. Blocks [256,512): x fp32->bf16 streaming convert;
// block 256 additionally emits the GEMM-swizzled bf16 weight array Wswz:
//   Wswz[((kstep*8+n)*64+lane)*8 + j] = Wcat[n*16+l16][kstep*32+quad*8+j]
// so the fused kernel's B-fragment loads are perfectly coalesced 1KB bursts.
__global__ __launch_bounds__(256) void fill_part1(
    const float* __restrict__ x, const int* __restrict__ ei,
    const float* __restrict__ Wself, const float* __restrict__ Wneigh,
    unsigned short* __restrict__ xb, unsigned int* __restrict__ gstore,
    unsigned short* __restrict__ offs, unsigned short* __restrict__ Wswz)
{
    const int t = threadIdx.x, b = blockIdx.x;
    if (b >= P_BLOCKS) {                 // streaming convert half of the grid
        const float4* x4 = reinterpret_cast<const float4*>(x);
        ushort4* xb4 = reinterpret_cast<ushort4*>(xb);
        const int j0 = (b - P_BLOCKS) * CONV_PER_BLOCK;
        for (int j = t; j < CONV_PER_BLOCK; j += 256) {
            float4 v = x4[j0 + j];
            ushort4 o;
            o.x = f2bf(v.x); o.y = f2bf(v.y); o.z = f2bf(v.z); o.w = f2bf(v.w);
            xb4[j0 + j] = o;
        }
        if (b == P_BLOCKS) {             // swizzled weight conversion (tiny)
            for (int idx = t; idx < 4096; idx += 256) {
                int kstep = idx >> 9, n = (idx >> 6) & 7, lane = idx & 63;
                int l16 = lane & 15, quad = lane >> 4;
                int c = n * 16 + l16;            // output column
                int kk = kstep * 32 + quad * 8;  // 0..255 (cat K)
                const float* sp = (kk < 128) ? (Wself + c * 128 + kk)
                                             : (Wneigh + c * 128 + kk - 128);
                float4 v0 = *reinterpret_cast<const float4*>(sp);
                float4 v1 = *reinterpret_cast<const float4*>(sp + 4);
                ushort4 o0, o1;
                o0.x = f2bf(v0.x); o0.y = f2bf(v0.y); o0.z = f2bf(v0.z); o0.w = f2bf(v0.w);
                o1.x = f2bf(v1.x); o1.y = f2bf(v1.y); o1.z = f2bf(v1.z); o1.w = f2bf(v1.w);
                *reinterpret_cast<ushort4*>(Wswz + idx * 8) = o0;
                *reinterpret_cast<ushort4*>(Wswz + idx * 8 + 4) = o1;
            }
        }
        return;
    }
    __shared__ unsigned long long eds[EPB];   // 25,000 B staged edges
    __shared__ unsigned int sorted_l[EPB];    // 12,500 B sorted u32 records
    __shared__ int hist[NBK_PAD];             // 7,168 B (reused as run counters)
    __shared__ int starts[NBK_PAD + 1];       // 7,172 B
    __shared__ int partial[256];
    for (int i = t; i < NBK_PAD; i += 256) hist[i] = 0;
    __syncthreads();
    const int e0 = b * EPB;
    for (int i = t; i < EPB; i += 256) {
        unsigned src = (unsigned)ei[e0 + i];
        unsigned dst = (unsigned)ei[E_EDGES + e0 + i];
        unsigned bk = dst >> 6;
        eds[i] = ((unsigned long long)bk << 32) | (src << 6) | (dst & 63u);
        atomicAdd(&hist[bk], 1);              // LDS atomic
    }
    __syncthreads();
    // exclusive scan of hist: thread t owns buckets [7t, 7t+7)
    int h[7], s = 0;
#pragma unroll
    for (int k = 0; k < 7; ++k) { h[k] = hist[t * 7 + k]; s += h[k]; }
    partial[t] = s;
    __syncthreads();
    for (int off = 1; off < 256; off <<= 1) {   // Hillis-Steele over 256
        int v = (t >= off) ? partial[t - off] : 0;
        __syncthreads();
        partial[t] += v;
        __syncthreads();
    }
    int run = partial[t] - s;                   // exclusive prefix
#pragma unroll
    for (int k = 0; k < 7; ++k) { starts[t * 7 + k] = run; run += h[k]; }
    if (t == 255) starts[NBK_PAD] = run;        // == EPB
    __syncthreads();
    for (int i = t; i < NBK_PAD; i += 256) hist[i] = 0;   // reuse as run ctr
    __syncthreads();
    for (int i = t; i < EPB; i += 256) {        // scatter into sorted order
        unsigned long long u = eds[i];
        unsigned bk = (unsigned)(u >> 32);
        int p = starts[bk] + atomicAdd(&hist[bk], 1);
        sorted_l[p] = (unsigned int)u;
    }
    __syncthreads();
    for (int i = t; i < EPB; i += 256)          // coalesced writeback
        gstore[b * EPB + i] = sorted_l[i];
    for (int i = t; i < OFFS_STRIDE; i += 256)
        offs[b * OFFS_STRIDE + i] = (unsigned short)starts[i];
}

// ---- pass 2 (FUSED): aggregate 2 buckets into LDS, then MFMA+ReLU+LN --------
// Block b (512 thr = 8 waves) owns nodes [128b, 128b+128) = buckets 2b, 2b+1.
// Agg phase: per-bucket LDS counting-sort (the round-0 structure, unchanged —
// rounds 1/2 showed ILP/TLP restructurings regress) with thread-group g = t>>8
// handling bucket 2b+g; gather accumulates in registers, writes bf16 means to
// the LDS tile nbT (NO global nb round-trip: saves 51.2 MB of HBM traffic and
// a kernel launch). GEMM phase: wave w owns rows [16w,16w+16); A from xb
// (global, coalesced) for K<128 and from nbT (LDS) for K>=128; B from the
// pre-swizzled Wswz (coalesced L2-hot 1KB bursts). LN epilogue in-wave.
// LDS 42.5 KB -> 3 blocks/CU (24 waves): one block's MFMA overlaps another's
// latency-bound gather (separate pipes).
__global__ __launch_bounds__(512, 6) void agg_gemm(
    const unsigned int* __restrict__ gstore, const unsigned short* __restrict__ offs,
    const unsigned short* __restrict__ xb, const unsigned short* __restrict__ Wswz,
    const float* __restrict__ bias, const float* __restrict__ gamma,
    const float* __restrict__ beta, float* __restrict__ out)
{
    __shared__ unsigned short nbT[128][NBPAD];   // 34,816 B bf16 neighbor means
    __shared__ unsigned int sortedq[2][QCAP];    // 6,144 B
    __shared__ int cnt_l[2][SLICE];
    __shared__ int run_l[2][SLICE];
    __shared__ int qs_l[2][SLICE + 1];
    const int t = threadIdx.x, b = blockIdx.x;
    const int g = t >> 8, st = t & 255;          // group g sorts bucket 2b+g
    const int bucket = b * 2 + g;
    if (st < SLICE) { cnt_l[g][st] = 0; run_l[g][st] = 0; }
    __syncthreads();
    int s0 = 0, s1 = 0;
    if (bucket < NBK) {                          // bucket 1563 doesn't exist
        s0 = offs[st * OFFS_STRIDE + bucket];
        s1 = offs[st * OFFS_STRIDE + bucket + 1];
    }
    const unsigned int* myrun = gstore + st * EPB;
    for (int j = s0; j < s1; ++j)                // pass A: histogram by node
        atomicAdd(&cnt_l[g][myrun[j] & 63u], 1);
    __syncthreads();
    if (st < SLICE) {                            // per-group shfl scan (wave 4g)
        int inc = cnt_l[g][st];
        for (int off = 1; off < 64; off <<= 1) {
            int u = __shfl_up(inc, off);
            if (st >= off) inc += u;
        }
        qs_l[g][st + 1] = inc;
        if (st == 0) qs_l[g][0] = 0;
    }
    __syncthreads();
    for (int j = s0; j < s1; ++j) {              // pass B: scatter (L1-hot)
        unsigned rec = myrun[j];
        int p = qs_l[g][rec & 63u] + atomicAdd(&run_l[g][rec & 63u], 1);
        if (p < QCAP) sortedq[g][p] = rec;
    }
    __syncthreads();
    // gather: wave w handles 16 nodes of bucket (w>>2); lane = subi x chunk
    const int wave = t >> 6, lane = t & 63;
    const int subi = lane >> 4, chunk = lane & 15;
    const int gg = wave >> 2;
    const uint4* x4 = reinterpret_cast<const uint4*>(xb);   // 16 uint4 per row
    for (int ln = (wave & 3) * 16; ln < (wave & 3) * 16 + 16; ++ln) {
        const int qb = qs_l[gg][ln], cc = qs_l[gg][ln + 1] - qb;
        float acc[8];
#pragma unroll
        for (int k = 0; k < 8; ++k) acc[k] = 0.f;
        for (int i = 0; i < cc; i += 4) {
            int idx = i + subi;
            if (idx < cc) {                      // quad-uniform branch
                unsigned rec = sortedq[gg][qb + idx];
                uint4 v = x4[(rec >> 6) * 16 + chunk];
                acc[0] += bflo(v.x); acc[1] += bfhi(v.x);
                acc[2] += bflo(v.y); acc[3] += bfhi(v.y);
                acc[4] += bflo(v.z); acc[5] += bfhi(v.z);
                acc[6] += bflo(v.w); acc[7] += bfhi(v.w);
            }
        }
#pragma unroll
        for (int k = 0; k < 8; ++k) {            // sum the 4 neighbor groups
            acc[k] += __shfl_xor(acc[k], 16);
            acc[k] += __shfl_xor(acc[k], 32);
        }
        if (subi == 0) {                         // bf16 mean -> LDS tile
            float inv = 1.0f / (float)(cc > 1 ? cc : 1);
            uint4 o;
            o.x = ((unsigned)f2bf(acc[1] * inv) << 16) | f2bf(acc[0] * inv);
            o.y = ((unsigned)f2bf(acc[3] * inv) << 16) | f2bf(acc[2] * inv);
            o.z = ((unsigned)f2bf(acc[5] * inv) << 16) | f2bf(acc[4] * inv);
            o.w = ((unsigned)f2bf(acc[7] * inv) << 16) | f2bf(acc[6] * inv);
            *reinterpret_cast<uint4*>(&nbT[gg * 64 + ln][chunk * 8]) = o;
        }
    }
    __syncthreads();
    // GEMM phase: wave owns rows [16w,16w+16) x 128 cols; K=256 over [x|nbT]
    const int l16 = lane & 15, quad = lane >> 4;
    f32x4 acc[8];
#pragma unroll
    for (int n = 0; n < 8; ++n) acc[n] = (f32x4)0.f;
    const int row = b * 128 + wave * 16 + l16;
    const int rowc = row < N_NODES ? row : N_NODES - 1;   // tail clamp
    const short8* wsz = reinterpret_cast<const short8*>(Wswz);
#pragma unroll
    for (int kstep = 0; kstep < 8; ++kstep) {
        short8 a;
        if (kstep < 4)
            a = *reinterpret_cast<const short8*>(xb + rowc * 128 + kstep * 32 + quad * 8);
        else
            a = *reinterpret_cast<const short8*>(&nbT[wave * 16 + l16][(kstep - 4) * 32 + quad * 8]);
#pragma unroll
        for (int n = 0; n < 8; ++n) {
            short8 bb = wsz[(kstep * 8 + n) * 64 + lane];   // coalesced, L2-hot
            acc[n] = __builtin_amdgcn_mfma_f32_16x16x32_bf16(a, bb, acc[n], 0, 0, 0);
        }
    }
    // epilogue: bias+ReLU+LN; row R's 128 cols live in the 16 lanes of one quad
    float bia[8], gam[8], bet[8];
#pragma unroll
    for (int n = 0; n < 8; ++n) {
        int col = n * 16 + l16;
        bia[n] = bias[col]; gam[n] = gamma[col]; bet[n] = beta[col];
    }
#pragma unroll
    for (int r = 0; r < 4; ++r) {
        float h[8], s = 0.f, q = 0.f;
#pragma unroll
        for (int n = 0; n < 8; ++n) {
            float v = acc[n][r] + bia[n];
            v = fmaxf(v, 0.f);
            h[n] = v; s += v; q += v * v;
        }
#pragma unroll
        for (int msk = 1; msk <= 8; msk <<= 1) {
            s += __shfl_xor(s, msk);
            q += __shfl_xor(q, msk);
        }
        const float mu = s * (1.f / 128.f);
        const float var = q * (1.f / 128.f) - mu * mu;
        const float rs = rsqrtf(var + LN_EPS);
        const int R = b * 128 + wave * 16 + quad * 4 + r;
        if (R < N_NODES) {
#pragma unroll
            for (int n = 0; n < 8; ++n)
                out[R * 128 + n * 16 + l16] = (h[n] - mu) * rs * gam[n] + bet[n];
        }
    }
}

extern "C" void kernel_launch(void* const* d_in, const int* in_sizes, int n_in,
                              void* d_out, int out_size, void* d_ws, size_t ws_size,
                              hipStream_t stream) {
    const float* x      = (const float*)d_in[0];
    const int*   ei     = (const int*)d_in[1];
    const float* Wself  = (const float*)d_in[2];
    const float* Wneigh = (const float*)d_in[3];
    const float* bias   = (const float*)d_in[4];
    const float* gamma  = (const float*)d_in[5];
    const float* beta   = (const float*)d_in[6];
    float* out = (float*)d_out;

    // ws layout (29.8 MB used)
    char* ws = (char*)d_ws;
    unsigned short* xb = (unsigned short*)ws;                       // 25,600,000
    unsigned int* gstore = (unsigned int*)(ws + 25600000);          //  3,200,000
    unsigned short* offs = (unsigned short*)(ws + 28800000);        //    800,768
    unsigned short* Wswz = (unsigned short*)(ws + 29601792);        //     65,536

    fill_part1<<<512, 256, 0, stream>>>(x, ei, Wself, Wneigh, xb, gstore, offs, Wswz);
    agg_gemm<<<TILE_BLKS, 512, 0, stream>>>(gstore, offs, xb, Wswz, bias, gamma, beta, out);
}

// Round 4
// 212.987 us; speedup vs baseline: 1.0784x; 1.0784x over previous
//
#include <hip/hip_runtime.h>
#include <hip/hip_bf16.h>

#define N_NODES 100000
#define E_EDGES 800000
#define LN_EPS 1e-5f

#define P_BLOCKS 256       // partition blocks
#define EPB 3125           // edges per partition block (800000/256, exact)
#define SLICE 64           // nodes per bucket (power of 2: bk = dst>>6)
#define NBK 1563           // ceil(100000/64); number of buckets = agg_gemm grid
#define NBK_PAD 1792       // 7*256 (scan convenience)
#define OFFS_STRIDE 1564   // per-block stored starts incl sentinel
#define QCAP 768           // bucket edge capacity (mean 512, sd 23 -> 11 sigma)
#define CONV_PER_BLOCK 12500   // 3.2M float4 groups of x / 256 convert blocks
#define NBPAD 136          // nbT row stride in shorts: 272B, 16B-aligned, ~2-way banks

typedef __attribute__((ext_vector_type(4))) float f32x4;
typedef __attribute__((ext_vector_type(8))) short short8;

__device__ __forceinline__ unsigned short f2bf(float f) {
    __hip_bfloat16 h = __float2bfloat16(f);
    return *reinterpret_cast<unsigned short*>(&h);
}
__device__ __forceinline__ float bflo(unsigned int u) { return __uint_as_float(u << 16); }
__device__ __forceinline__ float bfhi(unsigned int u) { return __uint_as_float(u & 0xffff0000u); }

// ---- pass 1: LDS counting-sort of edges by bucket, coalesced writeback ------
// Blocks [0,256): sort 3125 edges each, write block-major sorted records +
// per-bucket start offsets. Blocks [256,512): x fp32->bf16 streaming convert;
// block 256 additionally emits the GEMM-swizzled bf16 weight array Wswz:
//   Wswz[((kstep*8+n)*64+lane)*8 + j] = Wcat[n*16+l16][kstep*32+quad*8+j]
// so the fused kernel's B-fragment loads are perfectly coalesced 1KB bursts.
__global__ __launch_bounds__(256) void fill_part1(
    const float* __restrict__ x, const int* __restrict__ ei,
    const float* __restrict__ Wself, const float* __restrict__ Wneigh,
    unsigned short* __restrict__ xb, unsigned int* __restrict__ gstore,
    unsigned short* __restrict__ offs, unsigned short* __restrict__ Wswz)
{
    const int t = threadIdx.x, b = blockIdx.x;
    if (b >= P_BLOCKS) {                 // streaming convert half of the grid
        const float4* x4 = reinterpret_cast<const float4*>(x);
        ushort4* xb4 = reinterpret_cast<ushort4*>(xb);
        const int j0 = (b - P_BLOCKS) * CONV_PER_BLOCK;
        for (int j = t; j < CONV_PER_BLOCK; j += 256) {
            float4 v = x4[j0 + j];
            ushort4 o;
            o.x = f2bf(v.x); o.y = f2bf(v.y); o.z = f2bf(v.z); o.w = f2bf(v.w);
            xb4[j0 + j] = o;
        }
        if (b == P_BLOCKS) {             // swizzled weight conversion (tiny)
            for (int idx = t; idx < 4096; idx += 256) {
                int kstep = idx >> 9, n = (idx >> 6) & 7, lane = idx & 63;
                int l16 = lane & 15, quad = lane >> 4;
                int c = n * 16 + l16;            // output column
                int kk = kstep * 32 + quad * 8;  // 0..255 (cat K)
                const float* sp = (kk < 128) ? (Wself + c * 128 + kk)
                                             : (Wneigh + c * 128 + kk - 128);
                float4 v0 = *reinterpret_cast<const float4*>(sp);
                float4 v1 = *reinterpret_cast<const float4*>(sp + 4);
                ushort4 o0, o1;
                o0.x = f2bf(v0.x); o0.y = f2bf(v0.y); o0.z = f2bf(v0.z); o0.w = f2bf(v0.w);
                o1.x = f2bf(v1.x); o1.y = f2bf(v1.y); o1.z = f2bf(v1.z); o1.w = f2bf(v1.w);
                *reinterpret_cast<ushort4*>(Wswz + idx * 8) = o0;
                *reinterpret_cast<ushort4*>(Wswz + idx * 8 + 4) = o1;
            }
        }
        return;
    }
    __shared__ unsigned long long eds[EPB];   // 25,000 B staged edges
    __shared__ unsigned int sorted_l[EPB];    // 12,500 B sorted u32 records
    __shared__ int hist[NBK_PAD];             // 7,168 B (reused as run counters)
    __shared__ int starts[NBK_PAD + 1];       // 7,172 B
    __shared__ int partial[256];
    for (int i = t; i < NBK_PAD; i += 256) hist[i] = 0;
    __syncthreads();
    const int e0 = b * EPB;
    for (int i = t; i < EPB; i += 256) {
        unsigned src = (unsigned)ei[e0 + i];
        unsigned dst = (unsigned)ei[E_EDGES + e0 + i];
        unsigned bk = dst >> 6;
        eds[i] = ((unsigned long long)bk << 32) | (src << 6) | (dst & 63u);
        atomicAdd(&hist[bk], 1);              // LDS atomic
    }
    __syncthreads();
    // exclusive scan of hist: thread t owns buckets [7t, 7t+7)
    int h[7], s = 0;
#pragma unroll
    for (int k = 0; k < 7; ++k) { h[k] = hist[t * 7 + k]; s += h[k]; }
    partial[t] = s;
    __syncthreads();
    for (int off = 1; off < 256; off <<= 1) {   // Hillis-Steele over 256
        int v = (t >= off) ? partial[t - off] : 0;
        __syncthreads();
        partial[t] += v;
        __syncthreads();
    }
    int run = partial[t] - s;                   // exclusive prefix
#pragma unroll
    for (int k = 0; k < 7; ++k) { starts[t * 7 + k] = run; run += h[k]; }
    if (t == 255) starts[NBK_PAD] = run;        // == EPB
    __syncthreads();
    for (int i = t; i < NBK_PAD; i += 256) hist[i] = 0;   // reuse as run ctr
    __syncthreads();
    for (int i = t; i < EPB; i += 256) {        // scatter into sorted order
        unsigned long long u = eds[i];
        unsigned bk = (unsigned)(u >> 32);
        int p = starts[bk] + atomicAdd(&hist[bk], 1);
        sorted_l[p] = (unsigned int)u;
    }
    __syncthreads();
    for (int i = t; i < EPB; i += 256)          // coalesced writeback
        gstore[b * EPB + i] = sorted_l[i];
    for (int i = t; i < OFFS_STRIDE; i += 256)
        offs[b * OFFS_STRIDE + i] = (unsigned short)starts[i];
}

// ---- pass 2 (FUSED, round-0 packaging): per-bucket agg -> in-block GEMM -----
// Block b (256 thr = 4 waves) owns the 64 nodes of bucket b — EXACTLY the
// round-0 agg2 structure (1563 blocks, 6.1/CU residency, 16 nodes/wave,
// measured 49 us). Round-3's 512-thread/2-bucket packaging (3 blocks/CU)
// doubled the agg time; this keeps the proven shape. After the gather, the
// bf16 means stay in LDS (nbT) — no nb HBM round-trip (-51 MB) — and the
// block runs its own 64x128 MFMA tile (wave w: rows [16w,16w+16), K=256 over
// [xb | nbT]) + bias/ReLU/LN epilogue. B-frags from pre-swizzled Wswz (64 KB,
// L2-hot everywhere). GEMM adds ~350 MFMA-pipe cycles/wave, overlapping other
// blocks' latency-bound gathers. LDS 21.3 KB -> 7 blocks/CU (non-binding).
__global__ __launch_bounds__(256) void agg_gemm(
    const unsigned int* __restrict__ gstore, const unsigned short* __restrict__ offs,
    const unsigned short* __restrict__ xb, const unsigned short* __restrict__ Wswz,
    const float* __restrict__ bias, const float* __restrict__ gamma,
    const float* __restrict__ beta, float* __restrict__ out)
{
    __shared__ unsigned short nbT[SLICE][NBPAD];  // 17,408 B bf16 neighbor means
    __shared__ unsigned int sortedq[QCAP];        //  3,072 B
    __shared__ int cnt_l[SLICE];
    __shared__ int run_l[SLICE];
    __shared__ int qs_l[SLICE + 1];
    const int t = threadIdx.x, b = blockIdx.x;
    if (t < SLICE) { cnt_l[t] = 0; run_l[t] = 0; }
    __syncthreads();
    const int s0 = offs[t * OFFS_STRIDE + b];
    const int s1 = offs[t * OFFS_STRIDE + b + 1];
    const unsigned int* myrun = gstore + t * EPB;
    for (int j = s0; j < s1; ++j)             // pass A: histogram by node
        atomicAdd(&cnt_l[myrun[j] & 63u], 1);
    __syncthreads();
    if (t < SLICE) {                          // wave-0 shfl scan of 64 counts
        int inc = cnt_l[t];
        for (int off = 1; off < 64; off <<= 1) {
            int u = __shfl_up(inc, off);
            if (t >= off) inc += u;
        }
        qs_l[t + 1] = inc;
        if (t == 0) qs_l[0] = 0;
    }
    __syncthreads();
    for (int j = s0; j < s1; ++j) {           // pass B: scatter (L1-hot reread)
        unsigned rec = myrun[j];
        int p = qs_l[rec & 63u] + atomicAdd(&run_l[rec & 63u], 1);
        if (p < QCAP) sortedq[p] = rec;
    }
    __syncthreads();
    // quad-row gather: wave owns 16 nodes; lane = subi(4 edges) x chunk(16B)
    const int wave = t >> 6, lane = t & 63;
    const int subi = lane >> 4, chunk = lane & 15;
    const uint4* x4 = reinterpret_cast<const uint4*>(xb);   // 16 uint4 per row
    for (int ln = wave * 16; ln < wave * 16 + 16; ++ln) {
        const int qb = qs_l[ln], cc = qs_l[ln + 1] - qb;
        float acc[8];
#pragma unroll
        for (int k = 0; k < 8; ++k) acc[k] = 0.f;
        for (int i = 0; i < cc; i += 4) {
            int idx = i + subi;
            if (idx < cc) {                   // quad-uniform branch
                unsigned rec = sortedq[qb + idx];
                uint4 v = x4[(rec >> 6) * 16 + chunk];
                acc[0] += bflo(v.x); acc[1] += bfhi(v.x);
                acc[2] += bflo(v.y); acc[3] += bfhi(v.y);
                acc[4] += bflo(v.z); acc[5] += bfhi(v.z);
                acc[6] += bflo(v.w); acc[7] += bfhi(v.w);
            }
        }
#pragma unroll
        for (int k = 0; k < 8; ++k) {         // sum the 4 neighbor groups
            acc[k] += __shfl_xor(acc[k], 16);
            acc[k] += __shfl_xor(acc[k], 32);
        }
        if (subi == 0) {                      // bf16 mean -> LDS tile (no HBM)
            float inv = 1.0f / (float)(cc > 1 ? cc : 1);
            uint4 o;
            o.x = ((unsigned)f2bf(acc[1] * inv) << 16) | f2bf(acc[0] * inv);
            o.y = ((unsigned)f2bf(acc[3] * inv) << 16) | f2bf(acc[2] * inv);
            o.z = ((unsigned)f2bf(acc[5] * inv) << 16) | f2bf(acc[4] * inv);
            o.w = ((unsigned)f2bf(acc[7] * inv) << 16) | f2bf(acc[6] * inv);
            *reinterpret_cast<uint4*>(&nbT[ln][chunk * 8]) = o;
        }
    }
    __syncthreads();
    // GEMM phase: wave owns rows [16w,16w+16) x 128 cols; K=256 over [xb|nbT]
    const int l16 = lane & 15, quad = lane >> 4;
    f32x4 gacc[8];
#pragma unroll
    for (int n = 0; n < 8; ++n) gacc[n] = (f32x4)0.f;
    const int row = b * SLICE + wave * 16 + l16;
    const int rowc = row < N_NODES ? row : N_NODES - 1;   // tail clamp
    const short8* wsz = reinterpret_cast<const short8*>(Wswz);
#pragma unroll
    for (int kstep = 0; kstep < 8; ++kstep) {
        short8 a;
        if (kstep < 4)
            a = *reinterpret_cast<const short8*>(xb + rowc * 128 + kstep * 32 + quad * 8);
        else
            a = *reinterpret_cast<const short8*>(&nbT[wave * 16 + l16][(kstep - 4) * 32 + quad * 8]);
#pragma unroll
        for (int n = 0; n < 8; ++n) {
            short8 bb = wsz[(kstep * 8 + n) * 64 + lane];   // coalesced, L2-hot
            gacc[n] = __builtin_amdgcn_mfma_f32_16x16x32_bf16(a, bb, gacc[n], 0, 0, 0);
        }
    }
    // epilogue: bias+ReLU+LN; row R's 128 cols live in the 16 lanes of one quad
    float bia[8], gam[8], bet[8];
#pragma unroll
    for (int n = 0; n < 8; ++n) {
        int col = n * 16 + l16;
        bia[n] = bias[col]; gam[n] = gamma[col]; bet[n] = beta[col];
    }
#pragma unroll
    for (int r = 0; r < 4; ++r) {
        float h[8], s = 0.f, q = 0.f;
#pragma unroll
        for (int n = 0; n < 8; ++n) {
            float v = gacc[n][r] + bia[n];
            v = fmaxf(v, 0.f);
            h[n] = v; s += v; q += v * v;
        }
#pragma unroll
        for (int msk = 1; msk <= 8; msk <<= 1) {
            s += __shfl_xor(s, msk);
            q += __shfl_xor(q, msk);
        }
        const float mu = s * (1.f / 128.f);
        const float var = q * (1.f / 128.f) - mu * mu;
        const float rs = rsqrtf(var + LN_EPS);
        const int R = b * SLICE + wave * 16 + quad * 4 + r;
        if (R < N_NODES) {
#pragma unroll
            for (int n = 0; n < 8; ++n)
                out[R * 128 + n * 16 + l16] = (h[n] - mu) * rs * gam[n] + bet[n];
        }
    }
}

extern "C" void kernel_launch(void* const* d_in, const int* in_sizes, int n_in,
                              void* d_out, int out_size, void* d_ws, size_t ws_size,
                              hipStream_t stream) {
    const float* x      = (const float*)d_in[0];
    const int*   ei     = (const int*)d_in[1];
    const float* Wself  = (const float*)d_in[2];
    const float* Wneigh = (const float*)d_in[3];
    const float* bias   = (const float*)d_in[4];
    const float* gamma  = (const float*)d_in[5];
    const float* beta   = (const float*)d_in[6];
    float* out = (float*)d_out;

    // ws layout (29.8 MB used)
    char* ws = (char*)d_ws;
    unsigned short* xb = (unsigned short*)ws;                       // 25,600,000
    unsigned int* gstore = (unsigned int*)(ws + 25600000);          //  3,200,000
    unsigned short* offs = (unsigned short*)(ws + 28800000);        //    800,768
    unsigned short* Wswz = (unsigned short*)(ws + 29601792);        //     65,536

    fill_part1<<<512, 256, 0, stream>>>(x, ei, Wself, Wneigh, xb, gstore, offs, Wswz);
    agg_gemm<<<NBK, 256, 0, stream>>>(gstore, offs, xb, Wswz, bias, gamma, beta, out);
}

// Round 5
// 202.269 us; speedup vs baseline: 1.1355x; 1.0530x over previous
//
#include <hip/hip_runtime.h>
#include <hip/hip_bf16.h>

#define N_NODES 100000
#define E_EDGES 800000
#define LN_EPS 1e-5f

#define P_BLOCKS 256       // partition blocks
#define EPB 3125           // edges per partition block (800000/256, exact)
#define SLICE 64           // nodes per bucket (power of 2: bk = dst>>6)
#define NBK 1563           // ceil(100000/64); number of buckets = agg_gemm grid
#define NBK_PAD 1792       // 7*256 (scan convenience)
#define OFFS_STRIDE 1564   // per-block stored starts incl sentinel
#define QCAP 768           // bucket edge capacity (mean 512, sd 23 -> 11 sigma)
#define CONV_BLOCKS 1024   // streaming-convert blocks (grid = P_BLOCKS + CONV_BLOCKS)
#define CONV_TOTAL 3200000 // float4 groups in x
#define NBPAD 136          // nbT row stride in shorts: 272B, 16B-aligned, ~2-way banks

typedef __attribute__((ext_vector_type(4))) float f32x4;
typedef __attribute__((ext_vector_type(8))) short short8;

__device__ __forceinline__ unsigned short f2bf(float f) {
    __hip_bfloat16 h = __float2bfloat16(f);
    return *reinterpret_cast<unsigned short*>(&h);
}
__device__ __forceinline__ float bflo(unsigned int u) { return __uint_as_float(u << 16); }
__device__ __forceinline__ float bfhi(unsigned int u) { return __uint_as_float(u & 0xffff0000u); }

// ---- pass 1: LDS counting-sort of edges by bucket, coalesced writeback ------
// Blocks [0,256): sort 3125 edges each, write block-major sorted records +
// per-bucket start offsets. Blocks [256,1280): x fp32->bf16 streaming convert
// (1024 blocks for BW parallelism); block 256 additionally emits the
// GEMM-swizzled bf16 weight array Wswz:
//   Wswz[((kstep*8+n)*64+lane)*8 + j] = Wcat[n*16+l16][kstep*32+quad*8+j]
__global__ __launch_bounds__(256) void fill_part1(
    const float* __restrict__ x, const int* __restrict__ ei,
    const float* __restrict__ Wself, const float* __restrict__ Wneigh,
    unsigned short* __restrict__ xb, unsigned int* __restrict__ gstore,
    unsigned short* __restrict__ offs, unsigned short* __restrict__ Wswz)
{
    const int t = threadIdx.x, b = blockIdx.x;
    if (b >= P_BLOCKS) {                 // streaming convert most of the grid
        const float4* x4 = reinterpret_cast<const float4*>(x);
        ushort4* xb4 = reinterpret_cast<ushort4*>(xb);
        for (int j = (b - P_BLOCKS) * 256 + t; j < CONV_TOTAL; j += CONV_BLOCKS * 256) {
            float4 v = x4[j];
            ushort4 o;
            o.x = f2bf(v.x); o.y = f2bf(v.y); o.z = f2bf(v.z); o.w = f2bf(v.w);
            xb4[j] = o;
        }
        if (b == P_BLOCKS) {             // swizzled weight conversion (tiny)
            for (int idx = t; idx < 4096; idx += 256) {
                int kstep = idx >> 9, n = (idx >> 6) & 7, lane = idx & 63;
                int l16 = lane & 15, quad = lane >> 4;
                int c = n * 16 + l16;            // output column
                int kk = kstep * 32 + quad * 8;  // 0..255 (cat K)
                const float* sp = (kk < 128) ? (Wself + c * 128 + kk)
                                             : (Wneigh + c * 128 + kk - 128);
                float4 v0 = *reinterpret_cast<const float4*>(sp);
                float4 v1 = *reinterpret_cast<const float4*>(sp + 4);
                ushort4 o0, o1;
                o0.x = f2bf(v0.x); o0.y = f2bf(v0.y); o0.z = f2bf(v0.z); o0.w = f2bf(v0.w);
                o1.x = f2bf(v1.x); o1.y = f2bf(v1.y); o1.z = f2bf(v1.z); o1.w = f2bf(v1.w);
                *reinterpret_cast<ushort4*>(Wswz + idx * 8) = o0;
                *reinterpret_cast<ushort4*>(Wswz + idx * 8 + 4) = o1;
            }
        }
        return;
    }
    __shared__ unsigned long long eds[EPB];   // 25,000 B staged edges
    __shared__ unsigned int sorted_l[EPB];    // 12,500 B sorted u32 records
    __shared__ int hist[NBK_PAD];             // 7,168 B (reused as run counters)
    __shared__ int starts[NBK_PAD + 1];       // 7,172 B
    __shared__ int partial[256];
    for (int i = t; i < NBK_PAD; i += 256) hist[i] = 0;
    __syncthreads();
    const int e0 = b * EPB;
    for (int i = t; i < EPB; i += 256) {
        unsigned src = (unsigned)ei[e0 + i];
        unsigned dst = (unsigned)ei[E_EDGES + e0 + i];
        unsigned bk = dst >> 6;
        eds[i] = ((unsigned long long)bk << 32) | (src << 6) | (dst & 63u);
        atomicAdd(&hist[bk], 1);              // LDS atomic
    }
    __syncthreads();
    // exclusive scan of hist: thread t owns buckets [7t, 7t+7)
    int h[7], s = 0;
#pragma unroll
    for (int k = 0; k < 7; ++k) { h[k] = hist[t * 7 + k]; s += h[k]; }
    partial[t] = s;
    __syncthreads();
    for (int off = 1; off < 256; off <<= 1) {   // Hillis-Steele over 256
        int v = (t >= off) ? partial[t - off] : 0;
        __syncthreads();
        partial[t] += v;
        __syncthreads();
    }
    int run = partial[t] - s;                   // exclusive prefix
#pragma unroll
    for (int k = 0; k < 7; ++k) { starts[t * 7 + k] = run; run += h[k]; }
    if (t == 255) starts[NBK_PAD] = run;        // == EPB
    __syncthreads();
    for (int i = t; i < NBK_PAD; i += 256) hist[i] = 0;   // reuse as run ctr
    __syncthreads();
    for (int i = t; i < EPB; i += 256) {        // scatter into sorted order
        unsigned long long u = eds[i];
        unsigned bk = (unsigned)(u >> 32);
        int p = starts[bk] + atomicAdd(&hist[bk], 1);
        sorted_l[p] = (unsigned int)u;
    }
    __syncthreads();
    for (int i = t; i < EPB; i += 256)          // coalesced writeback
        gstore[b * EPB + i] = sorted_l[i];
    for (int i = t; i < OFFS_STRIDE; i += 256)
        offs[b * OFFS_STRIDE + i] = (unsigned short)starts[i];
}

// ---- pass 2 (FUSED): per-bucket agg (round-0 shape) -> B-reusing GEMM -------
// Block b (256 thr = 4 waves) owns the 64 nodes of bucket b; agg phase is
// byte-identical to the proven round-0 agg2 (49 us). bf16 means stay in LDS.
// GEMM phase (re-tiled vs round 4): wave w owns ALL 64 rows x cols
// [32w, 32w+32) as m=4 row-tiles x n=2 — each B-fragment is loaded ONCE per
// wave and reused 4x from registers, cutting Wswz traffic 4x (400->100 MB L2)
// and making the block's 16 KB of xb A-rows L1-hot across waves. LN needs a
// cross-wave reduce (cols split over waves): 2 KB partials aliased onto the
// dead sortedq + one extra barrier. LDS 21.3 KB -> 7 blocks/CU (non-binding).
__global__ __launch_bounds__(256) void agg_gemm(
    const unsigned int* __restrict__ gstore, const unsigned short* __restrict__ offs,
    const unsigned short* __restrict__ xb, const unsigned short* __restrict__ Wswz,
    const float* __restrict__ bias, const float* __restrict__ gamma,
    const float* __restrict__ beta, float* __restrict__ out)
{
    __shared__ unsigned short nbT[SLICE][NBPAD];  // 17,408 B bf16 neighbor means
    __shared__ unsigned int sortedq[QCAP];        //  3,072 B (reused as LN partials)
    __shared__ int cnt_l[SLICE];
    __shared__ int run_l[SLICE];
    __shared__ int qs_l[SLICE + 1];
    const int t = threadIdx.x, b = blockIdx.x;
    if (t < SLICE) { cnt_l[t] = 0; run_l[t] = 0; }
    __syncthreads();
    const int s0 = offs[t * OFFS_STRIDE + b];
    const int s1 = offs[t * OFFS_STRIDE + b + 1];
    const unsigned int* myrun = gstore + t * EPB;
    for (int j = s0; j < s1; ++j)             // pass A: histogram by node
        atomicAdd(&cnt_l[myrun[j] & 63u], 1);
    __syncthreads();
    if (t < SLICE) {                          // wave-0 shfl scan of 64 counts
        int inc = cnt_l[t];
        for (int off = 1; off < 64; off <<= 1) {
            int u = __shfl_up(inc, off);
            if (t >= off) inc += u;
        }
        qs_l[t + 1] = inc;
        if (t == 0) qs_l[0] = 0;
    }
    __syncthreads();
    for (int j = s0; j < s1; ++j) {           // pass B: scatter (L1-hot reread)
        unsigned rec = myrun[j];
        int p = qs_l[rec & 63u] + atomicAdd(&run_l[rec & 63u], 1);
        if (p < QCAP) sortedq[p] = rec;
    }
    __syncthreads();
    // quad-row gather: wave owns 16 nodes; lane = subi(4 edges) x chunk(16B)
    const int wave = t >> 6, lane = t & 63;
    const int subi = lane >> 4, chunk = lane & 15;
    const uint4* x4 = reinterpret_cast<const uint4*>(xb);   // 16 uint4 per row
    for (int ln = wave * 16; ln < wave * 16 + 16; ++ln) {
        const int qb = qs_l[ln], cc = qs_l[ln + 1] - qb;
        float acc[8];
#pragma unroll
        for (int k = 0; k < 8; ++k) acc[k] = 0.f;
        for (int i = 0; i < cc; i += 4) {
            int idx = i + subi;
            if (idx < cc) {                   // quad-uniform branch
                unsigned rec = sortedq[qb + idx];
                uint4 v = x4[(rec >> 6) * 16 + chunk];
                acc[0] += bflo(v.x); acc[1] += bfhi(v.x);
                acc[2] += bflo(v.y); acc[3] += bfhi(v.y);
                acc[4] += bflo(v.z); acc[5] += bfhi(v.z);
                acc[6] += bflo(v.w); acc[7] += bfhi(v.w);
            }
        }
#pragma unroll
        for (int k = 0; k < 8; ++k) {         // sum the 4 neighbor groups
            acc[k] += __shfl_xor(acc[k], 16);
            acc[k] += __shfl_xor(acc[k], 32);
        }
        if (subi == 0) {                      // bf16 mean -> LDS tile (no HBM)
            float inv = 1.0f / (float)(cc > 1 ? cc : 1);
            uint4 o;
            o.x = ((unsigned)f2bf(acc[1] * inv) << 16) | f2bf(acc[0] * inv);
            o.y = ((unsigned)f2bf(acc[3] * inv) << 16) | f2bf(acc[2] * inv);
            o.z = ((unsigned)f2bf(acc[5] * inv) << 16) | f2bf(acc[4] * inv);
            o.w = ((unsigned)f2bf(acc[7] * inv) << 16) | f2bf(acc[6] * inv);
            *reinterpret_cast<uint4*>(&nbT[ln][chunk * 8]) = o;
        }
    }
    __syncthreads();
    // GEMM phase: wave w = all 64 rows x cols [32w,32w+32); m=4 tiles, n=2.
    const int l16 = lane & 15, quad = lane >> 4;
    f32x4 gacc[4][2];
#pragma unroll
    for (int m = 0; m < 4; ++m) { gacc[m][0] = (f32x4)0.f; gacc[m][1] = (f32x4)0.f; }
    int rowsg[4];
#pragma unroll
    for (int m = 0; m < 4; ++m) {
        int r = b * SLICE + m * 16 + l16;
        rowsg[m] = r < N_NODES ? r : N_NODES - 1;   // tail clamp; store guarded
    }
    const short8* wsz = reinterpret_cast<const short8*>(Wswz);
#pragma unroll
    for (int kstep = 0; kstep < 8; ++kstep) {
        const short8 bfr0 = wsz[(kstep * 8 + wave * 2 + 0) * 64 + lane];  // 1KB coalesced
        const short8 bfr1 = wsz[(kstep * 8 + wave * 2 + 1) * 64 + lane];
#pragma unroll
        for (int m = 0; m < 4; ++m) {
            short8 a;
            if (kstep < 4)
                a = *reinterpret_cast<const short8*>(xb + rowsg[m] * 128 + kstep * 32 + quad * 8);
            else
                a = *reinterpret_cast<const short8*>(&nbT[m * 16 + l16][(kstep - 4) * 32 + quad * 8]);
            gacc[m][0] = __builtin_amdgcn_mfma_f32_16x16x32_bf16(a, bfr0, gacc[m][0], 0, 0, 0);
            gacc[m][1] = __builtin_amdgcn_mfma_f32_16x16x32_bf16(a, bfr1, gacc[m][1], 0, 0, 0);
        }
    }
    // epilogue: bias+ReLU, per-wave partial LN stats over its 32 cols,
    // cross-wave combine via LDS (sortedq is dead -> alias as float buffer).
    float bia[2], gam[2], bet[2];
#pragma unroll
    for (int nn = 0; nn < 2; ++nn) {
        int col = wave * 32 + nn * 16 + l16;
        bia[nn] = bias[col]; gam[nn] = gamma[col]; bet[nn] = beta[col];
    }
    float* redS = reinterpret_cast<float*>(sortedq);        // [4][64]
    float* redQ = redS + 256;                               // [4][64]
#pragma unroll
    for (int m = 0; m < 4; ++m) {
#pragma unroll
        for (int r = 0; r < 4; ++r) {
            float v0 = fmaxf(gacc[m][0][r] + bia[0], 0.f);
            float v1 = fmaxf(gacc[m][1][r] + bia[1], 0.f);
            gacc[m][0][r] = v0; gacc[m][1][r] = v1;          // keep h in regs
            float s = v0 + v1, q = v0 * v0 + v1 * v1;
#pragma unroll
            for (int msk = 1; msk <= 8; msk <<= 1) {         // reduce over l16
                s += __shfl_xor(s, msk);
                q += __shfl_xor(q, msk);
            }
            if (l16 == 0) {                                  // one lane per quad
                int Rl = m * 16 + quad * 4 + r;
                redS[wave * 64 + Rl] = s;
                redQ[wave * 64 + Rl] = q;
            }
        }
    }
    __syncthreads();
#pragma unroll
    for (int m = 0; m < 4; ++m) {
#pragma unroll
        for (int r = 0; r < 4; ++r) {
            const int Rl = m * 16 + quad * 4 + r;
            float s = redS[Rl] + redS[64 + Rl] + redS[128 + Rl] + redS[192 + Rl];
            float q = redQ[Rl] + redQ[64 + Rl] + redQ[128 + Rl] + redQ[192 + Rl];
            const float mu = s * (1.f / 128.f);
            const float var = q * (1.f / 128.f) - mu * mu;
            const float rs = rsqrtf(var + LN_EPS);
            const int R = b * SLICE + Rl;
            if (R < N_NODES) {
                out[R * 128 + wave * 32 + l16]      = (gacc[m][0][r] - mu) * rs * gam[0] + bet[0];
                out[R * 128 + wave * 32 + 16 + l16] = (gacc[m][1][r] - mu) * rs * gam[1] + bet[1];
            }
        }
    }
}

extern "C" void kernel_launch(void* const* d_in, const int* in_sizes, int n_in,
                              void* d_out, int out_size, void* d_ws, size_t ws_size,
                              hipStream_t stream) {
    const float* x      = (const float*)d_in[0];
    const int*   ei     = (const int*)d_in[1];
    const float* Wself  = (const float*)d_in[2];
    const float* Wneigh = (const float*)d_in[3];
    const float* bias   = (const float*)d_in[4];
    const float* gamma  = (const float*)d_in[5];
    const float* beta   = (const float*)d_in[6];
    float* out = (float*)d_out;

    // ws layout (29.8 MB used)
    char* ws = (char*)d_ws;
    unsigned short* xb = (unsigned short*)ws;                       // 25,600,000
    unsigned int* gstore = (unsigned int*)(ws + 25600000);          //  3,200,000
    unsigned short* offs = (unsigned short*)(ws + 28800000);        //    800,768
    unsigned short* Wswz = (unsigned short*)(ws + 29601792);        //     65,536

    fill_part1<<<P_BLOCKS + CONV_BLOCKS, 256, 0, stream>>>(x, ei, Wself, Wneigh, xb, gstore, offs, Wswz);
    agg_gemm<<<NBK, 256, 0, stream>>>(gstore, offs, xb, Wswz, bias, gamma, beta, out);
}

// Round 7
// 193.198 us; speedup vs baseline: 1.1888x; 1.0470x over previous
//
#include <hip/hip_runtime.h>
#include <hip/hip_bf16.h>

#define N_NODES 100000
#define E_EDGES 800000
#define LN_EPS 1e-5f

#define P_BLOCKS 256       // partition blocks
#define EPB 3125           // edges per partition block (800000/256, exact)
#define SLICE 64           // nodes per bucket (power of 2: bk = dst>>6)
#define NBK 1563           // ceil(100000/64); number of buckets = agg_gemm grid
#define NBK_PAD 1792       // 7*256 (scan convenience)
#define OFFS_STRIDE 1564   // per-block stored starts incl sentinel
#define QCAP 768           // bucket edge capacity (mean 512, sd 23 -> 11 sigma)
#define CONV_BLOCKS 1024   // streaming-convert blocks (grid = P_BLOCKS + CONV_BLOCKS)
#define CONV_TOTAL 3200000 // float4 groups in x
#define NBPAD 136          // nbT row stride in shorts: 272B, 16B-aligned, ~2-way banks

typedef __attribute__((ext_vector_type(4))) float f32x4;
typedef __attribute__((ext_vector_type(8))) short short8;

__device__ __forceinline__ unsigned short f2bf(float f) {
    __hip_bfloat16 h = __float2bfloat16(f);
    return *reinterpret_cast<unsigned short*>(&h);
}
__device__ __forceinline__ float bflo(unsigned int u) { return __uint_as_float(u << 16); }
__device__ __forceinline__ float bfhi(unsigned int u) { return __uint_as_float(u & 0xffff0000u); }

// ---- pass 1: LDS counting-sort of edges by bucket, coalesced writeback ------
// Blocks [0,256): sort 3125 edges each, write block-major sorted records +
// per-bucket start offsets. Blocks [256,1280): x fp32->bf16 streaming convert
// (1024 blocks — measured ~20us faster than 256 on the total); block 256 also
// emits the GEMM-swizzled bf16 weights:
//   Wswz[((kstep*8+n)*64+lane)*8 + j] = Wcat[n*16+l16][kstep*32+quad*8+j]
// NOTE round-6's branchless-gather variant (padded lists + dummy zeros row)
// tripped the graph-vs-eager determinism tripwire — reverted to the verified
// round-4 agg_gemm structure. Do not reintroduce without a determinism-safe
// scatter (LDS-atomic rank order is timing-dependent).
__global__ __launch_bounds__(256) void fill_part1(
    const float* __restrict__ x, const int* __restrict__ ei,
    const float* __restrict__ Wself, const float* __restrict__ Wneigh,
    unsigned short* __restrict__ xb, unsigned int* __restrict__ gstore,
    unsigned short* __restrict__ offs, unsigned short* __restrict__ Wswz)
{
    const int t = threadIdx.x, b = blockIdx.x;
    if (b >= P_BLOCKS) {                 // streaming convert most of the grid
        const float4* x4 = reinterpret_cast<const float4*>(x);
        ushort4* xb4 = reinterpret_cast<ushort4*>(xb);
        for (int j = (b - P_BLOCKS) * 256 + t; j < CONV_TOTAL; j += CONV_BLOCKS * 256) {
            float4 v = x4[j];
            ushort4 o;
            o.x = f2bf(v.x); o.y = f2bf(v.y); o.z = f2bf(v.z); o.w = f2bf(v.w);
            xb4[j] = o;
        }
        if (b == P_BLOCKS) {             // swizzled weight conversion (tiny)
            for (int idx = t; idx < 4096; idx += 256) {
                int kstep = idx >> 9, n = (idx >> 6) & 7, lane = idx & 63;
                int l16 = lane & 15, quad = lane >> 4;
                int c = n * 16 + l16;            // output column
                int kk = kstep * 32 + quad * 8;  // 0..255 (cat K)
                const float* sp = (kk < 128) ? (Wself + c * 128 + kk)
                                             : (Wneigh + c * 128 + kk - 128);
                float4 v0 = *reinterpret_cast<const float4*>(sp);
                float4 v1 = *reinterpret_cast<const float4*>(sp + 4);
                ushort4 o0, o1;
                o0.x = f2bf(v0.x); o0.y = f2bf(v0.y); o0.z = f2bf(v0.z); o0.w = f2bf(v0.w);
                o1.x = f2bf(v1.x); o1.y = f2bf(v1.y); o1.z = f2bf(v1.z); o1.w = f2bf(v1.w);
                *reinterpret_cast<ushort4*>(Wswz + idx * 8) = o0;
                *reinterpret_cast<ushort4*>(Wswz + idx * 8 + 4) = o1;
            }
        }
        return;
    }
    __shared__ unsigned long long eds[EPB];   // 25,000 B staged edges
    __shared__ unsigned int sorted_l[EPB];    // 12,500 B sorted u32 records
    __shared__ int hist[NBK_PAD];             // 7,168 B (reused as run counters)
    __shared__ int starts[NBK_PAD + 1];       // 7,172 B
    __shared__ int partial[256];
    for (int i = t; i < NBK_PAD; i += 256) hist[i] = 0;
    __syncthreads();
    const int e0 = b * EPB;
    for (int i = t; i < EPB; i += 256) {
        unsigned src = (unsigned)ei[e0 + i];
        unsigned dst = (unsigned)ei[E_EDGES + e0 + i];
        unsigned bk = dst >> 6;
        eds[i] = ((unsigned long long)bk << 32) | (src << 6) | (dst & 63u);
        atomicAdd(&hist[bk], 1);              // LDS atomic
    }
    __syncthreads();
    // exclusive scan of hist: thread t owns buckets [7t, 7t+7)
    int h[7], s = 0;
#pragma unroll
    for (int k = 0; k < 7; ++k) { h[k] = hist[t * 7 + k]; s += h[k]; }
    partial[t] = s;
    __syncthreads();
    for (int off = 1; off < 256; off <<= 1) {   // Hillis-Steele over 256
        int v = (t >= off) ? partial[t - off] : 0;
        __syncthreads();
        partial[t] += v;
        __syncthreads();
    }
    int run = partial[t] - s;                   // exclusive prefix
#pragma unroll
    for (int k = 0; k < 7; ++k) { starts[t * 7 + k] = run; run += h[k]; }
    if (t == 255) starts[NBK_PAD] = run;        // == EPB
    __syncthreads();
    for (int i = t; i < NBK_PAD; i += 256) hist[i] = 0;   // reuse as run ctr
    __syncthreads();
    for (int i = t; i < EPB; i += 256) {        // scatter into sorted order
        unsigned long long u = eds[i];
        unsigned bk = (unsigned)(u >> 32);
        int p = starts[bk] + atomicAdd(&hist[bk], 1);
        sorted_l[p] = (unsigned int)u;
    }
    __syncthreads();
    for (int i = t; i < EPB; i += 256)          // coalesced writeback
        gstore[b * EPB + i] = sorted_l[i];
    for (int i = t; i < OFFS_STRIDE; i += 256)
        offs[b * OFFS_STRIDE + i] = (unsigned short)starts[i];
}

// ---- pass 2 (FUSED, verified round-4 structure): per-bucket agg -> GEMM -----
// Block b (256 thr = 4 waves) owns the 64 nodes of bucket b — the proven
// round-0 agg shape (1563 blocks, 6.1/CU, 16 nodes/wave). bf16 means stay in
// LDS (nbT) — no nb HBM round-trip. GEMM phase: round-4 tiling (wave w =
// rows [16w,16w+16) x 128 cols; 8 B-frags/kstep from pre-swizzled Wswz,
// in-quad LN, single barrier). Round-5's B-reuse retile regressed (2x nbT
// bank conflicts + extra barrier); round-6's branchless gather tripped the
// determinism tripwire. This is the verified-best combination (85us @ R4).
__global__ __launch_bounds__(256) void agg_gemm(
    const unsigned int* __restrict__ gstore, const unsigned short* __restrict__ offs,
    const unsigned short* __restrict__ xb, const unsigned short* __restrict__ Wswz,
    const float* __restrict__ bias, const float* __restrict__ gamma,
    const float* __restrict__ beta, float* __restrict__ out)
{
    __shared__ unsigned short nbT[SLICE][NBPAD];  // 17,408 B bf16 neighbor means
    __shared__ unsigned int sortedq[QCAP];        //  3,072 B
    __shared__ int cnt_l[SLICE];
    __shared__ int run_l[SLICE];
    __shared__ int qs_l[SLICE + 1];
    const int t = threadIdx.x, b = blockIdx.x;
    if (t < SLICE) { cnt_l[t] = 0; run_l[t] = 0; }
    __syncthreads();
    const int s0 = offs[t * OFFS_STRIDE + b];
    const int s1 = offs[t * OFFS_STRIDE + b + 1];
    const unsigned int* myrun = gstore + t * EPB;
    for (int j = s0; j < s1; ++j)             // pass A: histogram by node
        atomicAdd(&cnt_l[myrun[j] & 63u], 1);
    __syncthreads();
    if (t < SLICE) {                          // wave-0 shfl scan of 64 counts
        int inc = cnt_l[t];
        for (int off = 1; off < 64; off <<= 1) {
            int u = __shfl_up(inc, off);
            if (t >= off) inc += u;
        }
        qs_l[t + 1] = inc;
        if (t == 0) qs_l[0] = 0;
    }
    __syncthreads();
    for (int j = s0; j < s1; ++j) {           // pass B: scatter (L1-hot reread)
        unsigned rec = myrun[j];
        int p = qs_l[rec & 63u] + atomicAdd(&run_l[rec & 63u], 1);
        if (p < QCAP) sortedq[p] = rec;
    }
    __syncthreads();
    // quad-row gather: wave owns 16 nodes; lane = subi(4 edges) x chunk(16B)
    const int wave = t >> 6, lane = t & 63;
    const int subi = lane >> 4, chunk = lane & 15;
    const uint4* x4 = reinterpret_cast<const uint4*>(xb);   // 16 uint4 per row
    for (int ln = wave * 16; ln < wave * 16 + 16; ++ln) {
        const int qb = qs_l[ln], cc = qs_l[ln + 1] - qb;
        float acc[8];
#pragma unroll
        for (int k = 0; k < 8; ++k) acc[k] = 0.f;
        for (int i = 0; i < cc; i += 4) {
            int idx = i + subi;
            if (idx < cc) {                   // quad-uniform branch
                unsigned rec = sortedq[qb + idx];
                uint4 v = x4[(rec >> 6) * 16 + chunk];
                acc[0] += bflo(v.x); acc[1] += bfhi(v.x);
                acc[2] += bflo(v.y); acc[3] += bfhi(v.y);
                acc[4] += bflo(v.z); acc[5] += bfhi(v.z);
                acc[6] += bflo(v.w); acc[7] += bfhi(v.w);
            }
        }
#pragma unroll
        for (int k = 0; k < 8; ++k) {         // sum the 4 neighbor groups
            acc[k] += __shfl_xor(acc[k], 16);
            acc[k] += __shfl_xor(acc[k], 32);
        }
        if (subi == 0) {                      // bf16 mean -> LDS tile (no HBM)
            float inv = 1.0f / (float)(cc > 1 ? cc : 1);
            uint4 o;
            o.x = ((unsigned)f2bf(acc[1] * inv) << 16) | f2bf(acc[0] * inv);
            o.y = ((unsigned)f2bf(acc[3] * inv) << 16) | f2bf(acc[2] * inv);
            o.z = ((unsigned)f2bf(acc[5] * inv) << 16) | f2bf(acc[4] * inv);
            o.w = ((unsigned)f2bf(acc[7] * inv) << 16) | f2bf(acc[6] * inv);
            *reinterpret_cast<uint4*>(&nbT[ln][chunk * 8]) = o;
        }
    }
    __syncthreads();
    // GEMM phase: wave owns rows [16w,16w+16) x 128 cols; K=256 over [xb|nbT]
    const int l16 = lane & 15, quad = lane >> 4;
    f32x4 gacc[8];
#pragma unroll
    for (int n = 0; n < 8; ++n) gacc[n] = (f32x4)0.f;
    const int row = b * SLICE + wave * 16 + l16;
    const int rowc = row < N_NODES ? row : N_NODES - 1;   // tail clamp
    const short8* wsz = reinterpret_cast<const short8*>(Wswz);
#pragma unroll
    for (int kstep = 0; kstep < 8; ++kstep) {
        short8 a;
        if (kstep < 4)
            a = *reinterpret_cast<const short8*>(xb + rowc * 128 + kstep * 32 + quad * 8);
        else
            a = *reinterpret_cast<const short8*>(&nbT[wave * 16 + l16][(kstep - 4) * 32 + quad * 8]);
#pragma unroll
        for (int n = 0; n < 8; ++n) {
            short8 bb = wsz[(kstep * 8 + n) * 64 + lane];   // coalesced, L2-hot
            gacc[n] = __builtin_amdgcn_mfma_f32_16x16x32_bf16(a, bb, gacc[n], 0, 0, 0);
        }
    }
    // epilogue: bias+ReLU+LN; row R's 128 cols live in the 16 lanes of one quad
    float bia[8], gam[8], bet[8];
#pragma unroll
    for (int n = 0; n < 8; ++n) {
        int col = n * 16 + l16;
        bia[n] = bias[col]; gam[n] = gamma[col]; bet[n] = beta[col];
    }
#pragma unroll
    for (int r = 0; r < 4; ++r) {
        float h[8], s = 0.f, q = 0.f;
#pragma unroll
        for (int n = 0; n < 8; ++n) {
            float v = gacc[n][r] + bia[n];
            v = fmaxf(v, 0.f);
            h[n] = v; s += v; q += v * v;
        }
#pragma unroll
        for (int msk = 1; msk <= 8; msk <<= 1) {
            s += __shfl_xor(s, msk);
            q += __shfl_xor(q, msk);
        }
        const float mu = s * (1.f / 128.f);
        const float var = q * (1.f / 128.f) - mu * mu;
        const float rs = rsqrtf(var + LN_EPS);
        const int R = b * SLICE + wave * 16 + quad * 4 + r;
        if (R < N_NODES) {
#pragma unroll
            for (int n = 0; n < 8; ++n)
                out[R * 128 + n * 16 + l16] = (h[n] - mu) * rs * gam[n] + bet[n];
        }
    }
}

extern "C" void kernel_launch(void* const* d_in, const int* in_sizes, int n_in,
                              void* d_out, int out_size, void* d_ws, size_t ws_size,
                              hipStream_t stream) {
    const float* x      = (const float*)d_in[0];
    const int*   ei     = (const int*)d_in[1];
    const float* Wself  = (const float*)d_in[2];
    const float* Wneigh = (const float*)d_in[3];
    const float* bias   = (const float*)d_in[4];
    const float* gamma  = (const float*)d_in[5];
    const float* beta   = (const float*)d_in[6];
    float* out = (float*)d_out;

    // ws layout (29.8 MB used)
    char* ws = (char*)d_ws;
    unsigned short* xb = (unsigned short*)ws;                       // 25,600,000
    unsigned int* gstore = (unsigned int*)(ws + 25600000);          //  3,200,000
    unsigned short* offs = (unsigned short*)(ws + 28800000);        //    800,768
    unsigned short* Wswz = (unsigned short*)(ws + 29601792);        //     65,536

    fill_part1<<<P_BLOCKS + CONV_BLOCKS, 256, 0, stream>>>(x, ei, Wself, Wneigh, xb, gstore, offs, Wswz);
    agg_gemm<<<NBK, 256, 0, stream>>>(gstore, offs, xb, Wswz, bias, gamma, beta, out);
}

// Round 8
// 193.050 us; speedup vs baseline: 1.1897x; 1.0008x over previous
//
#include <hip/hip_runtime.h>
#include <hip/hip_bf16.h>

#define N_NODES 100000
#define E_EDGES 800000
#define LN_EPS 1e-5f

#define P_BLOCKS 256       // partition blocks
#define EPB 3125           // edges per partition block (800000/256, exact)
#define SLICE 64           // nodes per bucket (power of 2: bk = dst>>6)
#define NBK 1563           // ceil(100000/64); number of buckets = agg_gemm grid
#define NBK_PAD 1792       // 7*256 (scan convenience)
#define OFFS_STRIDE 1564   // per-block stored starts incl sentinel
#define QCAP 768           // bucket edge capacity (mean 512, sd 23 -> 11 sigma)
#define CONV_BLOCKS 1024   // streaming-convert blocks (grid = P_BLOCKS + CONV_BLOCKS)
#define CONV_TOTAL 3200000 // float4 groups in x
#define NBPAD 136          // nbT row stride in shorts: 272B, 16B-aligned, ~2-way banks

typedef __attribute__((ext_vector_type(4))) float f32x4;
typedef __attribute__((ext_vector_type(8))) short short8;

__device__ __forceinline__ unsigned short f2bf(float f) {
    __hip_bfloat16 h = __float2bfloat16(f);
    return *reinterpret_cast<unsigned short*>(&h);
}
__device__ __forceinline__ float bflo(unsigned int u) { return __uint_as_float(u << 16); }
__device__ __forceinline__ float bfhi(unsigned int u) { return __uint_as_float(u & 0xffff0000u); }

// ---- pass 1: LDS counting-sort of edges by bucket, coalesced writeback ------
// Blocks [0,256): sort 3125 edges each, write block-major sorted records +
// per-bucket start offsets. Blocks [256,1280): x fp32->bf16 streaming convert
// (1024 blocks — measured ~20us faster than 256 on the total); block 256 also
// emits the GEMM-swizzled bf16 weights:
//   Wswz[((kstep*8+n)*64+lane)*8 + j] = Wcat[n*16+l16][kstep*32+quad*8+j]
__global__ __launch_bounds__(256) void fill_part1(
    const float* __restrict__ x, const int* __restrict__ ei,
    const float* __restrict__ Wself, const float* __restrict__ Wneigh,
    unsigned short* __restrict__ xb, unsigned int* __restrict__ gstore,
    unsigned short* __restrict__ offs, unsigned short* __restrict__ Wswz)
{
    const int t = threadIdx.x, b = blockIdx.x;
    if (b >= P_BLOCKS) {                 // streaming convert most of the grid
        const float4* x4 = reinterpret_cast<const float4*>(x);
        ushort4* xb4 = reinterpret_cast<ushort4*>(xb);
        for (int j = (b - P_BLOCKS) * 256 + t; j < CONV_TOTAL; j += CONV_BLOCKS * 256) {
            float4 v = x4[j];
            ushort4 o;
            o.x = f2bf(v.x); o.y = f2bf(v.y); o.z = f2bf(v.z); o.w = f2bf(v.w);
            xb4[j] = o;
        }
        if (b == P_BLOCKS) {             // swizzled weight conversion (tiny)
            for (int idx = t; idx < 4096; idx += 256) {
                int kstep = idx >> 9, n = (idx >> 6) & 7, lane = idx & 63;
                int l16 = lane & 15, quad = lane >> 4;
                int c = n * 16 + l16;            // output column
                int kk = kstep * 32 + quad * 8;  // 0..255 (cat K)
                const float* sp = (kk < 128) ? (Wself + c * 128 + kk)
                                             : (Wneigh + c * 128 + kk - 128);
                float4 v0 = *reinterpret_cast<const float4*>(sp);
                float4 v1 = *reinterpret_cast<const float4*>(sp + 4);
                ushort4 o0, o1;
                o0.x = f2bf(v0.x); o0.y = f2bf(v0.y); o0.z = f2bf(v0.z); o0.w = f2bf(v0.w);
                o1.x = f2bf(v1.x); o1.y = f2bf(v1.y); o1.z = f2bf(v1.z); o1.w = f2bf(v1.w);
                *reinterpret_cast<ushort4*>(Wswz + idx * 8) = o0;
                *reinterpret_cast<ushort4*>(Wswz + idx * 8 + 4) = o1;
            }
        }
        return;
    }
    __shared__ unsigned long long eds[EPB];   // 25,000 B staged edges
    __shared__ unsigned int sorted_l[EPB];    // 12,500 B sorted u32 records
    __shared__ int hist[NBK_PAD];             // 7,168 B (reused as run counters)
    __shared__ int starts[NBK_PAD + 1];       // 7,172 B
    __shared__ int partial[256];
    for (int i = t; i < NBK_PAD; i += 256) hist[i] = 0;
    __syncthreads();
    const int e0 = b * EPB;
    for (int i = t; i < EPB; i += 256) {
        unsigned src = (unsigned)ei[e0 + i];
        unsigned dst = (unsigned)ei[E_EDGES + e0 + i];
        unsigned bk = dst >> 6;
        eds[i] = ((unsigned long long)bk << 32) | (src << 6) | (dst & 63u);
        atomicAdd(&hist[bk], 1);              // LDS atomic
    }
    __syncthreads();
    // exclusive scan of hist: thread t owns buckets [7t, 7t+7)
    int h[7], s = 0;
#pragma unroll
    for (int k = 0; k < 7; ++k) { h[k] = hist[t * 7 + k]; s += h[k]; }
    partial[t] = s;
    __syncthreads();
    for (int off = 1; off < 256; off <<= 1) {   // Hillis-Steele over 256
        int v = (t >= off) ? partial[t - off] : 0;
        __syncthreads();
        partial[t] += v;
        __syncthreads();
    }
    int run = partial[t] - s;                   // exclusive prefix
#pragma unroll
    for (int k = 0; k < 7; ++k) { starts[t * 7 + k] = run; run += h[k]; }
    if (t == 255) starts[NBK_PAD] = run;        // == EPB
    __syncthreads();
    for (int i = t; i < NBK_PAD; i += 256) hist[i] = 0;   // reuse as run ctr
    __syncthreads();
    for (int i = t; i < EPB; i += 256) {        // scatter into sorted order
        unsigned long long u = eds[i];
        unsigned bk = (unsigned)(u >> 32);
        int p = starts[bk] + atomicAdd(&hist[bk], 1);
        sorted_l[p] = (unsigned int)u;
    }
    __syncthreads();
    for (int i = t; i < EPB; i += 256)          // coalesced writeback
        gstore[b * EPB + i] = sorted_l[i];
    for (int i = t; i < OFFS_STRIDE; i += 256)
        offs[b * OFFS_STRIDE + i] = (unsigned short)starts[i];
}

// ---- pass 2 (FUSED): per-bucket agg -> wave-private GEMM, NO join barrier ---
// Block b (256 thr = 4 waves) owns the 64 nodes of bucket b — the proven
// round-0 agg shape. bf16 means stay in LDS (nbT). vs round 7: the
// __syncthreads() between gather and GEMM is REMOVED — in the R4 tiling,
// GEMM wave w reads only nbT rows [16w,16w+16), which wave w itself produced
// in the gather; xb rows, Wswz B-frags, in-quad LN and output rows are all
// wave-private too. With no barrier, a wave that finishes its gather flows
// straight into its MFMA phase while sibling waves are still latency-stalled
// on gathers — the GEMM's ~36us hides under the gather's memory latency.
// One explicit lgkmcnt(0) drains the nbT ds_writes before the GEMM's LDS
// reads (within-wave ordering insurance; no cross-wave data crosses here).
// VGPR must stay <=64 (cliff halves occupancy above it; R7 measured 56).
__global__ __launch_bounds__(256) void agg_gemm(
    const unsigned int* __restrict__ gstore, const unsigned short* __restrict__ offs,
    const unsigned short* __restrict__ xb, const unsigned short* __restrict__ Wswz,
    const float* __restrict__ bias, const float* __restrict__ gamma,
    const float* __restrict__ beta, float* __restrict__ out)
{
    __shared__ unsigned short nbT[SLICE][NBPAD];  // 17,408 B bf16 neighbor means
    __shared__ unsigned int sortedq[QCAP];        //  3,072 B
    __shared__ int cnt_l[SLICE];
    __shared__ int run_l[SLICE];
    __shared__ int qs_l[SLICE + 1];
    const int t = threadIdx.x, b = blockIdx.x;
    if (t < SLICE) { cnt_l[t] = 0; run_l[t] = 0; }
    __syncthreads();
    const int s0 = offs[t * OFFS_STRIDE + b];
    const int s1 = offs[t * OFFS_STRIDE + b + 1];
    const unsigned int* myrun = gstore + t * EPB;
    for (int j = s0; j < s1; ++j)             // pass A: histogram by node
        atomicAdd(&cnt_l[myrun[j] & 63u], 1);
    __syncthreads();
    if (t < SLICE) {                          // wave-0 shfl scan of 64 counts
        int inc = cnt_l[t];
        for (int off = 1; off < 64; off <<= 1) {
            int u = __shfl_up(inc, off);
            if (t >= off) inc += u;
        }
        qs_l[t + 1] = inc;
        if (t == 0) qs_l[0] = 0;
    }
    __syncthreads();
    for (int j = s0; j < s1; ++j) {           // pass B: scatter (L1-hot reread)
        unsigned rec = myrun[j];
        int p = qs_l[rec & 63u] + atomicAdd(&run_l[rec & 63u], 1);
        if (p < QCAP) sortedq[p] = rec;
    }
    __syncthreads();                          // last block-wide barrier
    // quad-row gather: wave owns 16 nodes; lane = subi(4 edges) x chunk(16B)
    const int wave = t >> 6, lane = t & 63;
    const int subi = lane >> 4, chunk = lane & 15;
    const uint4* x4 = reinterpret_cast<const uint4*>(xb);   // 16 uint4 per row
    for (int ln = wave * 16; ln < wave * 16 + 16; ++ln) {
        const int qb = qs_l[ln], cc = qs_l[ln + 1] - qb;
        float acc[8];
#pragma unroll
        for (int k = 0; k < 8; ++k) acc[k] = 0.f;
        for (int i = 0; i < cc; i += 4) {
            int idx = i + subi;
            if (idx < cc) {                   // quad-uniform branch
                unsigned rec = sortedq[qb + idx];
                uint4 v = x4[(rec >> 6) * 16 + chunk];
                acc[0] += bflo(v.x); acc[1] += bfhi(v.x);
                acc[2] += bflo(v.y); acc[3] += bfhi(v.y);
                acc[4] += bflo(v.z); acc[5] += bfhi(v.z);
                acc[6] += bflo(v.w); acc[7] += bfhi(v.w);
            }
        }
#pragma unroll
        for (int k = 0; k < 8; ++k) {         // sum the 4 neighbor groups
            acc[k] += __shfl_xor(acc[k], 16);
            acc[k] += __shfl_xor(acc[k], 32);
        }
        if (subi == 0) {                      // bf16 mean -> LDS tile (no HBM)
            float inv = 1.0f / (float)(cc > 1 ? cc : 1);
            uint4 o;
            o.x = ((unsigned)f2bf(acc[1] * inv) << 16) | f2bf(acc[0] * inv);
            o.y = ((unsigned)f2bf(acc[3] * inv) << 16) | f2bf(acc[2] * inv);
            o.z = ((unsigned)f2bf(acc[5] * inv) << 16) | f2bf(acc[4] * inv);
            o.w = ((unsigned)f2bf(acc[7] * inv) << 16) | f2bf(acc[6] * inv);
            *reinterpret_cast<uint4*>(&nbT[ln][chunk * 8]) = o;
        }
    }
    // NO __syncthreads() here: GEMM wave w reads only its own nbT rows.
    // Drain this wave's nbT ds_writes before its LDS reads (cheap insurance;
    // dependent ops are memory ops, so the "memory" clobber orders them).
    asm volatile("s_waitcnt lgkmcnt(0)" ::: "memory");
    // GEMM phase: wave owns rows [16w,16w+16) x 128 cols; K=256 over [xb|nbT]
    const int l16 = lane & 15, quad = lane >> 4;
    f32x4 gacc[8];
#pragma unroll
    for (int n = 0; n < 8; ++n) gacc[n] = (f32x4)0.f;
    const int row = b * SLICE + wave * 16 + l16;
    const int rowc = row < N_NODES ? row : N_NODES - 1;   // tail clamp
    const short8* wsz = reinterpret_cast<const short8*>(Wswz);
#pragma unroll
    for (int kstep = 0; kstep < 8; ++kstep) {
        short8 a;
        if (kstep < 4)
            a = *reinterpret_cast<const short8*>(xb + rowc * 128 + kstep * 32 + quad * 8);
        else
            a = *reinterpret_cast<const short8*>(&nbT[wave * 16 + l16][(kstep - 4) * 32 + quad * 8]);
#pragma unroll
        for (int n = 0; n < 8; ++n) {
            short8 bb = wsz[(kstep * 8 + n) * 64 + lane];   // coalesced, L2-hot
            gacc[n] = __builtin_amdgcn_mfma_f32_16x16x32_bf16(a, bb, gacc[n], 0, 0, 0);
        }
    }
    // epilogue: bias+ReLU+LN; row R's 128 cols live in the 16 lanes of one quad
    float bia[8], gam[8], bet[8];
#pragma unroll
    for (int n = 0; n < 8; ++n) {
        int col = n * 16 + l16;
        bia[n] = bias[col]; gam[n] = gamma[col]; bet[n] = beta[col];
    }
#pragma unroll
    for (int r = 0; r < 4; ++r) {
        float h[8], s = 0.f, q = 0.f;
#pragma unroll
        for (int n = 0; n < 8; ++n) {
            float v = gacc[n][r] + bia[n];
            v = fmaxf(v, 0.f);
            h[n] = v; s += v; q += v * v;
        }
#pragma unroll
        for (int msk = 1; msk <= 8; msk <<= 1) {
            s += __shfl_xor(s, msk);
            q += __shfl_xor(q, msk);
        }
        const float mu = s * (1.f / 128.f);
        const float var = q * (1.f / 128.f) - mu * mu;
        const float rs = rsqrtf(var + LN_EPS);
        const int R = b * SLICE + wave * 16 + quad * 4 + r;
        if (R < N_NODES) {
#pragma unroll
            for (int n = 0; n < 8; ++n)
                out[R * 128 + n * 16 + l16] = (h[n] - mu) * rs * gam[n] + bet[n];
        }
    }
}

extern "C" void kernel_launch(void* const* d_in, const int* in_sizes, int n_in,
                              void* d_out, int out_size, void* d_ws, size_t ws_size,
                              hipStream_t stream) {
    const float* x      = (const float*)d_in[0];
    const int*   ei     = (const int*)d_in[1];
    const float* Wself  = (const float*)d_in[2];
    const float* Wneigh = (const float*)d_in[3];
    const float* bias   = (const float*)d_in[4];
    const float* gamma  = (const float*)d_in[5];
    const float* beta   = (const float*)d_in[6];
    float* out = (float*)d_out;

    // ws layout (29.8 MB used)
    char* ws = (char*)d_ws;
    unsigned short* xb = (unsigned short*)ws;                       // 25,600,000
    unsigned int* gstore = (unsigned int*)(ws + 25600000);          //  3,200,000
    unsigned short* offs = (unsigned short*)(ws + 28800000);        //    800,768
    unsigned short* Wswz = (unsigned short*)(ws + 29601792);        //     65,536

    fill_part1<<<P_BLOCKS + CONV_BLOCKS, 256, 0, stream>>>(x, ei, Wself, Wneigh, xb, gstore, offs, Wswz);
    agg_gemm<<<NBK, 256, 0, stream>>>(gstore, offs, xb, Wswz, bias, gamma, beta, out);
}